// Round 13
// baseline (702.204 us; speedup 1.0000x reference)
//
#include <hip/hip_runtime.h>
#include <hip/hip_fp16.h>

#define DEVFN __device__ __forceinline__

constexpr int C   = 64;
constexpr int Hh  = 160, Ww = 160, HW = Hh * Ww;   // 25600
constexpr int B   = 2;
constexpr int P   = B * HW;                        // 51200
constexpr int NSET = 32;

typedef _Float16 f16;
typedef f16   f16x8 __attribute__((ext_vector_type(8)));
typedef float f32x4 __attribute__((ext_vector_type(4)));

// NOTE-1..22: see history.
// NOTE-23 (r31): coop mega-kernel: launch silently failed (output zero).
// NOTE-24 (r32): coop + occupancy-query under GRAPH CAPTURE poisons the
// capture ("container failed twice").
// NOTE-25 (r33): NEVER call cooperative/occupancy APIs in kernel_launch
// (graph capture). Grid-wide sync instead via MANUAL device-scope
// barriers in a plain <<<512,256>>> launch: __launch_bounds__(256,2)
// makes 2 blk/CU provable (VGPR<=256, LDS 42.9KBx2<160KB), grid=512=
// 2x256CU so all blocks co-resident; atomic counter + __threadfence()
// release/acquire handles cross-XCD L2 (write-back+invalidate); three
// distinct counters, zeroed per replay by a captured memset.

struct KParams {
    const float *inp, *ln1w, *ln1b, *c11aw, *c11ab;
    f16 *x1, *u1;
    float *meanb;
    const float *kbw, *kbb, *conv3w, *beta, *w4, *ln2w, *ln2b, *b4,
                *w5, *b5, *gamma, *conv3b;
    f16 *wp, *wk;
    float *cbuf;
    const float *c2aw, *c2ab, *c2bw, *c2bb, *attg;
    f16 *att;
    const float *c11bw, *c11bb;
    f16 *uf;
    const float *ga1, *scaw, *scab;
    f16 *xmid;
    float *out;
    unsigned *bar;
};

constexpr int ATTS = 340;                // f16 units; 170 u32

// ======================= stage bodies =======================

DEVFN void stageA_body(const KParams& p, int item, int tid, unsigned* SMEM) {
    const f32x4 zero = {0.f, 0.f, 0.f, 0.f};
    if (item < 800) {
        float* SM = (float*)SMEM;
        int wv = tid >> 6, lane = tid & 63;
        int m = lane & 15, q = lane >> 4;

        int rg = item & 7, ii = item >> 3;
        int b  = ii / 50, j = ii % 50;
        int hw0 = rg * 3200 + j * 64 + wv * 16;

        f16x8 A[4][2];
#pragma unroll
        for (int mt = 0; mt < 4; mt++)
#pragma unroll
            for (int c = 0; c < 2; c++) {
                const float* src = p.c11aw + (mt * 16 + m) * 64 + c * 32 + q * 8;
                f32x4 w0 = *(const f32x4*)src;
                f32x4 w1 = *(const f32x4*)(src + 4);
                f16x8 a;
                a[0] = (f16)w0[0]; a[1] = (f16)w0[1];
                a[2] = (f16)w0[2]; a[3] = (f16)w0[3];
                a[4] = (f16)w1[0]; a[5] = (f16)w1[1];
                a[6] = (f16)w1[2]; a[7] = (f16)w1[3];
                A[mt][c] = a;
            }

        float lnwv[16], lnbv[16];
#pragma unroll
        for (int c = 0; c < 2; c++)
#pragma unroll
            for (int j2 = 0; j2 < 8; j2++) {
                int k = c * 32 + q * 8 + j2;
                lnwv[c * 8 + j2] = p.ln1w[k];
                lnbv[c * 8 + j2] = p.ln1b[k];
            }
        float bco[16];
#pragma unroll
        for (int mt = 0; mt < 4; mt++)
#pragma unroll
            for (int r = 0; r < 4; r++)
                bco[mt * 4 + r] = p.c11ab[mt * 16 + q * 4 + r];

        const float* ib = p.inp + (size_t)b * C * HW + hw0 + m;
        float vin[16];
#pragma unroll
        for (int c = 0; c < 2; c++)
#pragma unroll
            for (int j2 = 0; j2 < 8; j2++)
                vin[c * 8 + j2] = ib[(size_t)(c * 32 + q * 8 + j2) * HW];

        float s = 0.f, s2 = 0.f;
#pragma unroll
        for (int i = 0; i < 16; i++) { s += vin[i]; s2 += vin[i] * vin[i]; }
        s  += __shfl_xor(s, 16);  s  += __shfl_xor(s, 32);
        s2 += __shfl_xor(s2, 16); s2 += __shfl_xor(s2, 32);
        float mu  = s * (1.f / 64.f);
        float var = fmaxf(s2 * (1.f / 64.f) - mu * mu, 0.f);
        float r   = rsqrtf(var + 1e-6f);

        f16* xo = p.x1 + (size_t)b * C * HW + hw0 + m;
        f16x8 BX[2];
        float vsum[16];
#pragma unroll
        for (int c = 0; c < 2; c++)
#pragma unroll
            for (int j2 = 0; j2 < 8; j2++) {
                float v = (vin[c * 8 + j2] - mu) * r * lnwv[c * 8 + j2] + lnbv[c * 8 + j2];
                BX[c][j2] = (f16)v;
                vsum[c * 8 + j2] = v;
                xo[(size_t)(c * 32 + q * 8 + j2) * HW] = (f16)v;
            }

        f32x4 acc[4];
#pragma unroll
        for (int mt = 0; mt < 4; mt++) {
            acc[mt] = __builtin_amdgcn_mfma_f32_16x16x32_f16(A[mt][0], BX[0], zero, 0, 0, 0);
            acc[mt] = __builtin_amdgcn_mfma_f32_16x16x32_f16(A[mt][1], BX[1], acc[mt], 0, 0, 0);
        }
        f16* uo = p.u1 + (size_t)b * C * HW + hw0 + m;
#pragma unroll
        for (int mt = 0; mt < 4; mt++)
#pragma unroll
            for (int r2 = 0; r2 < 4; r2++) {
                int co = mt * 16 + q * 4 + r2;
                uo[(size_t)co * HW] = (f16)(acc[mt][r2] + bco[mt * 4 + r2]);
            }

#pragma unroll
        for (int i = 0; i < 16; i++) {
            float v = vsum[i];
            v += __shfl_xor(v, 1);
            v += __shfl_xor(v, 2);
            v += __shfl_xor(v, 4);
            v += __shfl_xor(v, 8);
            vsum[i] = v;
        }
        if (m == 0) {
#pragma unroll
            for (int c = 0; c < 2; c++)
#pragma unroll
                for (int j2 = 0; j2 < 8; j2++)
                    SM[wv * 64 + c * 32 + q * 8 + j2] = vsum[c * 8 + j2];
        }
        __syncthreads();
        if (tid < 64) {
            float a = SM[0 * 64 + tid] + SM[1 * 64 + tid] +
                      SM[2 * 64 + tid] + SM[3 * 64 + tid];
            atomicAdd(&p.meanb[b * 64 + tid], a * (1.f / HW));
        }
    } else {
        int e = (item - 800) * 256 + tid;
        if (e < 131072) {
            int j = e & 7, lane = (e >> 3) & 63, c = (e >> 9) & 1,
                mt = (e >> 10) & 7, g = e >> 13;
            int m = lane & 15, q = lane >> 4;
            int row = mt * 16 + m, s = row >> 2, o = row & 3;
            int k = c * 32 + q * 8 + j;
            float v = 0.f;
            if (k < 36)       v = p.kbw[(size_t)s * 2304 + g * 144 + o * 36 + k];
            else if (k == 36) v = p.kbb[s * 64 + g * 4 + o];
            p.wp[e] = (f16)v;
        } else if (e < 151552) {
            int e2 = e - 131072;
            int j = e2 & 7, lane = (e2 >> 3) & 63, seg = e2 >> 9;
            int m = lane & 15, q = lane >> 4;
            float v = 0.f;
            if (seg < 8) {
                int mt = seg >> 1, c = seg & 1, k = c * 32 + q * 8 + j;
                v = p.c11aw[(mt * 16 + m) * 64 + k];
            } else if (seg < 16) {
                int s3 = seg - 8, mt = s3 >> 1, c = s3 & 1, k = c * 32 + q * 8 + j;
                int co = mt * 16 + m;
                v = p.conv3w[co * 64 + k] * p.beta[co];
            } else if (seg < 32) {
                int s3 = seg - 16, mt = s3 >> 1, c = s3 & 1, k = c * 32 + q * 8 + j;
                v = p.w4[(mt * 16 + m) * 64 + k] * p.ln2w[k];
            } else {
                int s3 = seg - 32, mt = s3 >> 1, c = s3 & 1, k = c * 32 + q * 8 + j;
                int co = mt * 16 + m;
                v = p.w5[co * 64 + k] * p.gamma[co];
            }
            p.wk[e2] = (f16)v;
        } else if (e < 151808) {
            int t = e - 151552;
            if (t < 64) {
                p.cbuf[t] = p.conv3b[t] * p.beta[t];
            } else if (t < 192) {
                int j = t - 64;
                float a = 0.f;
#pragma unroll 1
                for (int ci = 0; ci < 64; ci++)
                    a = fmaf(p.w4[j * 64 + ci], p.ln2b[ci], a);
                p.cbuf[t] = a + p.b4[j];
            } else {
                int co = t - 192;
                p.cbuf[t] = p.b5[co] * p.gamma[co];
            }
        }
    }
}

DEVFN void stageB_body(const KParams& p, int item, int tid, unsigned* SMEM) {
    if (item < 800) {
        unsigned* XSa = SMEM;                  // 64*77 = 4928 u32
        float*    Wf  = (float*)(SMEM + 4928); // 1184 f32
        f16* XS = (f16*)XSa;
        int rg = item & 7, ii = item >> 3;
        int b  = ii / 50;
        int rem = ii % 50;
        int hp  = rg * 10 + rem / 5;
        int cb  = rem % 5;
        int h0  = hp * 2;

        float wreg[5];
#pragma unroll
        for (int i = 0; i < 5; i++) {
            int e = tid + i * 256;
            float v = 0.f;
            if (e < 576)       v = p.c2aw[e];
            else if (e < 608)  v = p.c2ab[e - 576];
            else if (e < 1120) v = p.c2bw[e - 608];
            else if (e < 1152) v = p.c2bb[e - 1120];
            else if (e < 1184) v = p.attg[e - 1152];
            wreg[i] = v;
        }
        unsigned vreg[18];
        {
            const unsigned* x32 = (const unsigned*)p.x1;
#pragma unroll
            for (int i = 0; i < 18; i++) {
                int e = tid + i * 256;
                int ch = e / 72, r2 = e - ch * 72, row = r2 / 18, cu = r2 - row * 18;
                int y = h0 - 1 + row;
                int xu = cb * 16 - 1 + cu;
                unsigned v = 0u;
                if ((unsigned)y < (unsigned)Hh && (unsigned)xu < 80u)
                    v = x32[((size_t)(b * C + ch) * HW >> 1) + y * 80 + xu];
                vreg[i] = v;
            }
        }
#pragma unroll
        for (int i = 0; i < 5; i++) {
            int e = tid + i * 256;
            if (e < 1184) Wf[e] = wreg[i];
        }
#pragma unroll
        for (int i = 0; i < 18; i++) {
            int e = tid + i * 256;
            int ch = e / 72, r2 = e - ch * 72, row = r2 / 18, cu = r2 - row * 18;
            XSa[ch * 77 + row * 19 + cu] = vreg[i];
        }
        __syncthreads();

        {
            int wv = tid >> 6, lane = tid & 63;
            int i = lane & 15, q = lane >> 4;
            int rr = wv >> 1;
            int px = (wv & 1) * 16 + i;
            int w_ = cb * 32 + px;
            int hw = (h0 + rr) * Ww + w_;

            float t[8];
#pragma unroll
            for (int j = 0; j < 8; j++) {
                int o = q * 8 + j;
                float acc = Wf[576 + o];
#pragma unroll
                for (int k = 0; k < 2; k++) {
                    const f16* xc = XS + (2 * o + k) * 154 + rr * 38 + px + 1;
                    const float* wr = &Wf[(o * 2 + k) * 9];
#pragma unroll
                    for (int kh = 0; kh < 3; kh++)
#pragma unroll
                        for (int kw = 0; kw < 3; kw++)
                            acc = fmaf(wr[kh * 3 + kw], (float)xc[kh * 38 + kw], acc);
                }
                t[j] = acc;
            }

            float g_[8], g2_[8];
#pragma unroll
            for (int j = 0; j < 8; j++) g_[j] = t[j] * __shfl_xor(t[j], 32);
#pragma unroll
            for (int j = 0; j < 8; j++) g2_[j] = __shfl_xor(g_[j], 16);
            float glo[8], ghi[8];
            bool hiq = (q & 1);
#pragma unroll
            for (int j = 0; j < 8; j++) {
                glo[j] = hiq ? g2_[j] : g_[j];
                ghi[j] = hiq ? g_[j] : g2_[j];
            }

            f16* ad = p.att + (size_t)b * NSET * HW + hw;
#pragma unroll
            for (int j = 0; j < 8; j++) {
                int s = q * 8 + j;
                float acc = Wf[1120 + s];
                const float* wr = &Wf[608 + s * 16];
#pragma unroll
                for (int c = 0; c < 8; c++) acc = fmaf(wr[c], glo[c], acc);
#pragma unroll
                for (int c = 0; c < 8; c++) acc = fmaf(wr[8 + c], ghi[c], acc);
                ad[(size_t)s * HW] = (f16)(acc * Wf[1152 + s]);
            }
        }
    } else {
        unsigned* UBa = SMEM;                 // 4*8*82 = 2624 u32
        float*    wsm = (float*)(SMEM + 2624);// 404 f32
        f16* UB = (f16*)UBa;
        int pv = item - 800;
        int rg = pv & 7, ii = pv >> 3;
        int g  = ii / 10;
        int rem = ii % 10;
        int b  = rem / 5;
        int hA = (rg * 5 + rem % 5) * 4;

        float wreg[2];
#pragma unroll
        for (int i = 0; i < 2; i++) {
            int e = tid + i * 256;
            float v = 0.f;
            if (e < 400) {
                int o = e / 100, r2 = e - o * 100, cl = r2 / 25, tp = r2 - cl * 25;
                v = p.c11bw[(((g * 4 + o) * 4) + cl) * 25 + tp];
            }
            wreg[i] = v;
        }
        unsigned vreg[10];
        {
            const unsigned* u132 = (const unsigned*)p.u1;
#pragma unroll
            for (int i = 0; i < 10; i++) {
                int e = tid + i * 256;
                int cl = e / 640, r = (e / 80) & 7, xw = e % 80;
                int y = hA - 2 + r;
                unsigned v = 0u;
                if ((unsigned)y < (unsigned)Hh)
                    v = u132[((size_t)(b * C + g * 4 + cl) * HW >> 1) + y * 80 + xw];
                vreg[i] = v;
            }
        }
#pragma unroll
        for (int i = 0; i < 2; i++) {
            int e = tid + i * 256;
            if (e < 400) wsm[e] = wreg[i];
        }
        if (tid < 4) wsm[400 + tid] = p.c11bb[g * 4 + tid];
#pragma unroll
        for (int i = 0; i < 10; i++) {
            int e = tid + i * 256;
            int cl = e / 640, r = (e / 80) & 7, xw = e % 80;
            UBa[cl * 656 + r * 82 + 1 + xw] = vreg[i];
        }
        if (tid < 64) {
            int cl = tid >> 4, r = (tid >> 1) & 7, side = tid & 1;
            UBa[cl * 656 + r * 82 + side * 81] = 0u;
        }
        __syncthreads();

        if (tid < 160) {
            int w_ = tid;
            int hw0 = hA * Ww + w_;

            float acc[16];
#pragma unroll
            for (int i = 0; i < 16; i++) acc[i] = wsm[400 + (i & 3)];

#pragma unroll 1
            for (int cl = 0; cl < 4; cl++) {
                const f16* src = UB + cl * 1312;
                float tv[40];
#pragma unroll
                for (int r = 0; r < 8; r++)
#pragma unroll
                    for (int kw = 0; kw < 5; kw++)
                        tv[r * 5 + kw] = (float)src[r * 164 + w_ + kw];
#pragma unroll
                for (int o = 0; o < 4; o++) {
                    const float* wr = &wsm[(o * 4 + cl) * 25];
#pragma unroll
                    for (int kh = 0; kh < 5; kh++)
#pragma unroll
                        for (int kw = 0; kw < 5; kw++) {
                            float wv = wr[kh * 5 + kw];
                            acc[0 * 4 + o] = fmaf(wv, tv[(kh + 0) * 5 + kw], acc[0 * 4 + o]);
                            acc[1 * 4 + o] = fmaf(wv, tv[(kh + 1) * 5 + kw], acc[1 * 4 + o]);
                            acc[2 * 4 + o] = fmaf(wv, tv[(kh + 2) * 5 + kw], acc[2 * 4 + o]);
                            acc[3 * 4 + o] = fmaf(wv, tv[(kh + 3) * 5 + kw], acc[3 * 4 + o]);
                        }
                }
            }
            f16* dst = p.uf + (size_t)(b * C + g * 4) * HW;
#pragma unroll
            for (int o = 0; o < 4; o++)
#pragma unroll
                for (int px = 0; px < 4; px++)
                    dst[o * HW + hw0 + px * Ww] = (f16)acc[px * 4 + o];
        }
    }
}

DEVFN void stageC_body(const KParams& p, int item, int tid, unsigned* SMEM) {
    const f32x4 zero = {0.f, 0.f, 0.f, 0.f};
    unsigned* UFa  = SMEM;                 // 16*4*82 = 5248 u32
    unsigned* ATTa = SMEM + 5248;          // 32*170 = 5440 u32
    float*    SCB  = (float*)(SMEM + 10688);
    f16* UF  = (f16*)UFa;
    f16* ATT = (f16*)ATTa;
    int rg  = item & 7, ii = item >> 3;
    int gq  = ii / 20;
    int rem = ii % 20;
    int b   = rem / 10;
    int h0  = rg * 20 + (rem % 10) * 2;
    int hw0 = h0 * Ww;
    int wv  = tid >> 6, lane = tid & 63;
    int m   = lane & 15, q = lane >> 4;
    int g   = gq * 4 + wv;

    {
        const unsigned* uf32 = (const unsigned*)p.uf;
        unsigned vreg[20];
#pragma unroll
        for (int i = 0; i < 20; i++) {
            int e = tid + i * 256;
            int ch = e / 320, r = (e / 80) & 3, xw = e % 80;
            int y = h0 - 1 + r;
            unsigned v = 0u;
            if ((unsigned)y < (unsigned)Hh)
                v = uf32[((size_t)(b * C + gq * 16 + ch) * HW >> 1) + y * 80 + xw];
            vreg[i] = v;
        }
#pragma unroll
        for (int i = 0; i < 20; i++) {
            int e = tid + i * 256;
            int ch = e / 320, r = (e / 80) & 3, xw = e % 80;
            UFa[ch * 328 + r * 82 + 1 + xw] = vreg[i];
        }
        if (tid < 128) {
            int ch = tid >> 3, r = (tid >> 1) & 3, side = tid & 1;
            UFa[ch * 328 + r * 82 + side * 81] = 0u;
        }
    }
    {
        const unsigned* ab32 =
            (const unsigned*)(p.att + (size_t)b * NSET * HW + hw0);
        unsigned vreg[20];
#pragma unroll
        for (int i = 0; i < 20; i++) {
            int e = tid + i * 256;
            int s = e / 160, pw = e % 160;
            vreg[i] = ab32[(size_t)s * (HW >> 1) + pw];
        }
#pragma unroll
        for (int i = 0; i < 20; i++) {
            int e = tid + i * 256;
            int s = e / 160, pw = e % 160;
            ATTa[s * 170 + pw] = vreg[i];
        }
    }

    {
        float mv = p.meanb[b * 64 + lane];
        float p0 = p.scaw[(g * 4 + 0) * 64 + lane] * mv;
        float p1 = p.scaw[(g * 4 + 1) * 64 + lane] * mv;
        float p2 = p.scaw[(g * 4 + 2) * 64 + lane] * mv;
        float p3 = p.scaw[(g * 4 + 3) * 64 + lane] * mv;
#pragma unroll
        for (int o = 32; o > 0; o >>= 1) {
            p0 += __shfl_down(p0, o);
            p1 += __shfl_down(p1, o);
            p2 += __shfl_down(p2, o);
            p3 += __shfl_down(p3, o);
        }
        if (lane == 0) {
            SCB[wv * 4 + 0] = p0 + p.scab[g * 4 + 0];
            SCB[wv * 4 + 1] = p1 + p.scab[g * 4 + 1];
            SCB[wv * 4 + 2] = p2 + p.scab[g * 4 + 2];
            SCB[wv * 4 + 3] = p3 + p.scab[g * 4 + 3];
        }
    }

    f16x8 A[8][2];
    const f16* wpg = p.wp + (size_t)g * 8 * 2 * 64 * 8;
#pragma unroll
    for (int mt = 0; mt < 8; mt++)
#pragma unroll
        for (int c = 0; c < 2; c++)
            A[mt][c] = *(const f16x8*)(wpg + ((mt * 2 + c) * 64 + lane) * 8);

    int off0[8];
#pragma unroll
    for (int j = 0; j < 8; j++) {
        int i = q * 8 + j;
        int cl = i / 9, rr = i - cl * 9, kh = rr / 3, kw = rr - kh * 3;
        off0[j] = (wv * 4 + cl) * 656 + kh * 164 + kw;
    }
    int off1[4];
#pragma unroll
    for (int j = 0; j < 4; j++) {
        int i = 32 + j;
        int rr = i - 27, kh = rr / 3, kw = rr - kh * 3;
        off1[j] = (wv * 4 + 3) * 656 + kh * 164 + kw;
    }

    float gav[4];
#pragma unroll
    for (int r = 0; r < 4; r++) gav[r] = p.ga1[g * 4 + r];

    __syncthreads();
    float scb[4];
#pragma unroll
    for (int r = 0; r < 4; r++) scb[r] = SCB[wv * 4 + r];

#pragma unroll 1
    for (int t = 0; t < 20; ++t) {
        int tr = t / 10, col0 = (t - tr * 10) * 16;
        int tbase = tr * 164 + col0 + m + 1;
        int pxb   = tr * 160 + col0 + m;

        f16x8 B0, B1;
#pragma unroll
        for (int j = 0; j < 8; j++) B0[j] = UF[off0[j] + tbase];
        if (q == 0) {
#pragma unroll
            for (int j = 0; j < 4; j++) B1[j] = UF[off1[j] + tbase];
            B1[4] = (f16)1.f;
            B1[5] = (f16)0.f; B1[6] = (f16)0.f; B1[7] = (f16)0.f;
        } else {
#pragma unroll
            for (int j = 0; j < 8; j++) B1[j] = (f16)0.f;
        }

        f32x4 acc[8];
#pragma unroll
        for (int mt = 0; mt < 8; mt++) {
            acc[mt] = __builtin_amdgcn_mfma_f32_16x16x32_f16(A[mt][0], B0, zero, 0, 0, 0);
            acc[mt] = __builtin_amdgcn_mfma_f32_16x16x32_f16(A[mt][1], B1, acc[mt], 0, 0, 0);
        }

        float o4[4] = {0.f, 0.f, 0.f, 0.f};
#pragma unroll
        for (int mt = 0; mt < 8; mt++) {
            float av = (float)ATT[(mt * 4 + q) * ATTS + pxb];
#pragma unroll
            for (int r = 0; r < 4; r++) o4[r] = fmaf(av, acc[mt][r], o4[r]);
        }
#pragma unroll
        for (int r = 0; r < 4; r++) {
            o4[r] += __shfl_xor(o4[r], 16);
            o4[r] += __shfl_xor(o4[r], 32);
        }
        if (q == 0) {
            int hw = hw0 + pxb;
#pragma unroll
            for (int r = 0; r < 4; r++) {
                int co = g * 4 + r;
                float cf = (float)UF[(wv * 4 + r) * 656 + (tr + 1) * 164 + 2 + col0 + m];
                p.xmid[(size_t)(b * C + co) * HW + hw] =
                    (f16)((o4[r] * gav[r] + cf) * scb[r]);
            }
        }
    }
}

DEVFN void stageD_body(const KParams& p, int item, int tid, unsigned* SMEM) {
    const f32x4 zero = {0.f, 0.f, 0.f, 0.f};
    float* CONST = (float*)SMEM;              // 256 f32
    f16*   TBUF  = (f16*)(SMEM + 256);        // 4*1152 f16
    int wv = tid >> 6, lane = tid & 63;
    int m = lane & 15, q = lane >> 4;
    f16* T = TBUF + wv * 1152;

    CONST[tid] = p.cbuf[tid];

    f16x8 A3[4][2], A4[8][2], A5[4][2];
#pragma unroll
    for (int mt = 0; mt < 4; mt++)
#pragma unroll
        for (int c = 0; c < 2; c++) {
            A3[mt][c] = *(const f16x8*)(p.wk + ((8 + mt * 2 + c) * 64 + lane) * 8);
            A5[mt][c] = *(const f16x8*)(p.wk + ((32 + mt * 2 + c) * 64 + lane) * 8);
        }
#pragma unroll
    for (int mt = 0; mt < 8; mt++)
#pragma unroll
        for (int c = 0; c < 2; c++)
            A4[mt][c] = *(const f16x8*)(p.wk + ((16 + mt * 2 + c) * 64 + lane) * 8);
    __syncthreads();

    float c3i[16], b5g[16];
#pragma unroll
    for (int mt = 0; mt < 4; mt++)
#pragma unroll
        for (int r = 0; r < 4; r++) {
            c3i[mt * 4 + r] = CONST[mt * 16 + q * 4 + r];
            b5g[mt * 4 + r] = CONST[192 + mt * 16 + q * 4 + r];
        }

    int rg = item & 7, ii = item >> 3;
    int b  = ii / 50, j = ii % 50;
    int hw0 = rg * 3200 + j * 64 + wv * 16;
    const f16* xb = p.xmid + (size_t)b * C * HW + hw0 + m;
    const float* ib = p.inp + (size_t)b * C * HW + hw0 + m;
    float* ob = p.out + (size_t)b * C * HW + hw0 + m;

    f16x8 BX[2];
#pragma unroll
    for (int c = 0; c < 2; c++)
#pragma unroll
        for (int j2 = 0; j2 < 8; j2++)
            BX[c][j2] = xb[(size_t)(c * 32 + q * 8 + j2) * HW];

    f32x4 accY[4];
#pragma unroll
    for (int mt = 0; mt < 4; mt++) {
        accY[mt] = __builtin_amdgcn_mfma_f32_16x16x32_f16(A3[mt][0], BX[0], zero, 0, 0, 0);
        accY[mt] = __builtin_amdgcn_mfma_f32_16x16x32_f16(A3[mt][1], BX[1], accY[mt], 0, 0, 0);
    }
    float y[16];
#pragma unroll
    for (int mt = 0; mt < 4; mt++)
#pragma unroll
        for (int r = 0; r < 4; r++) {
            int co = mt * 16 + q * 4 + r;
            y[mt * 4 + r] = ib[(size_t)co * HW] + accY[mt][r] + c3i[mt * 4 + r];
        }

    float s = 0.f, s2 = 0.f;
#pragma unroll
    for (int i = 0; i < 16; i++) { s += y[i]; s2 += y[i] * y[i]; }
    s  += __shfl_xor(s, 16);  s  += __shfl_xor(s, 32);
    s2 += __shfl_xor(s2, 16); s2 += __shfl_xor(s2, 32);
    float mu  = s * (1.f / 64.f);
    float var = fmaxf(s2 * (1.f / 64.f) - mu * mu, 0.f);
    float rr  = rsqrtf(var + 1e-6f);

#pragma unroll
    for (int mt = 0; mt < 4; mt++)
#pragma unroll
        for (int r = 0; r < 4; r++)
            T[m * 72 + mt * 16 + q * 4 + r] = (f16)(y[mt * 4 + r] - mu);
    f16x8 BV[2];
#pragma unroll
    for (int c = 0; c < 2; c++)
#pragma unroll
        for (int j2 = 0; j2 < 8; j2++)
            BV[c][j2] = T[m * 72 + c * 32 + q * 8 + j2];

    f32x4 accT[8];
#pragma unroll
    for (int mt = 0; mt < 8; mt++) {
        accT[mt] = __builtin_amdgcn_mfma_f32_16x16x32_f16(A4[mt][0], BV[0], zero, 0, 0, 0);
        accT[mt] = __builtin_amdgcn_mfma_f32_16x16x32_f16(A4[mt][1], BV[1], accT[mt], 0, 0, 0);
    }

#pragma unroll
    for (int mt = 0; mt < 4; mt++)
#pragma unroll
        for (int r = 0; r < 4; r++) {
            int j2 = mt * 16 + q * 4 + r;
            float t1 = rr * accT[mt][r] + CONST[64 + j2];
            float t2 = rr * accT[mt + 4][r] + CONST[128 + j2];
            T[m * 72 + j2] = (f16)(t1 * t2);
        }
    f16x8 BG[2];
#pragma unroll
    for (int c = 0; c < 2; c++)
#pragma unroll
        for (int j2 = 0; j2 < 8; j2++)
            BG[c][j2] = T[m * 72 + c * 32 + q * 8 + j2];

    f32x4 accO[4];
#pragma unroll
    for (int mt = 0; mt < 4; mt++) {
        accO[mt] = __builtin_amdgcn_mfma_f32_16x16x32_f16(A5[mt][0], BG[0], zero, 0, 0, 0);
        accO[mt] = __builtin_amdgcn_mfma_f32_16x16x32_f16(A5[mt][1], BG[1], accO[mt], 0, 0, 0);
    }
#pragma unroll
    for (int mt = 0; mt < 4; mt++)
#pragma unroll
        for (int r = 0; r < 4; r++) {
            int co = mt * 16 + q * 4 + r;
            ob[(size_t)co * HW] = y[mt * 4 + r] + accO[mt][r] + b5g[mt * 4 + r];
        }
}

// manual device-scope grid barrier (all blocks co-resident by occupancy)
DEVFN void gridbar(unsigned* ctr, int tid, unsigned nblk) {
    __syncthreads();          // all waves in block done with prior work
    __threadfence();          // device-scope release (L2 write-back)
    if (tid == 0) {
        __hip_atomic_fetch_add(ctr, 1u, __ATOMIC_ACQ_REL,
                               __HIP_MEMORY_SCOPE_AGENT);
        while (__hip_atomic_load(ctr, __ATOMIC_ACQUIRE,
                                 __HIP_MEMORY_SCOPE_AGENT) < nblk)
            __builtin_amdgcn_s_sleep(8);
    }
    __syncthreads();
    __threadfence();          // acquire side (invalidate stale lines)
}

// ======================= mega kernel (plain launch) =======================
__global__ __launch_bounds__(256, 2) void kmega(KParams p) {
    __shared__ __align__(16) unsigned SMEM[10720];   // 42880 B
    int tid = threadIdx.x;
    int gs  = gridDim.x;
    unsigned nblk = gridDim.x;

    for (int item = blockIdx.x; item < 1393; item += gs) {
        __syncthreads();
        stageA_body(p, item, tid, SMEM);
    }
    gridbar(p.bar + 0, tid, nblk);
    for (int item = blockIdx.x; item < 2080; item += gs) {
        __syncthreads();
        stageB_body(p, item, tid, SMEM);
    }
    gridbar(p.bar + 1, tid, nblk);
    for (int item = blockIdx.x; item < 640; item += gs) {
        __syncthreads();
        stageC_body(p, item, tid, SMEM);
    }
    gridbar(p.bar + 2, tid, nblk);
    for (int item = blockIdx.x; item < 800; item += gs) {
        __syncthreads();
        stageD_body(p, item, tid, SMEM);
    }
}

extern "C" void kernel_launch(void* const* d_in, const int* in_sizes, int n_in,
                              void* d_out, int out_size, void* d_ws, size_t ws_size,
                              hipStream_t stream) {
    (void)in_sizes; (void)n_in; (void)out_size; (void)ws_size;

    const float* inp     = (const float*)d_in[0];
    const float* ln1_w   = (const float*)d_in[1];
    const float* ln1_b   = (const float*)d_in[2];
    const float* ln2_w   = (const float*)d_in[3];
    const float* ln2_b   = (const float*)d_in[4];
    const float* sca_w   = (const float*)d_in[5];
    const float* sca_b   = (const float*)d_in[6];
    const float* c11a_w  = (const float*)d_in[7];
    const float* c11a_b  = (const float*)d_in[8];
    const float* c11b_w  = (const float*)d_in[9];
    const float* c11b_b  = (const float*)d_in[10];
    const float* c2a_w   = (const float*)d_in[11];
    const float* c2a_b   = (const float*)d_in[12];
    const float* c2b_w   = (const float*)d_in[13];
    const float* c2b_b   = (const float*)d_in[14];
    const float* conv3_w = (const float*)d_in[15];
    const float* conv3_b = (const float*)d_in[16];
    const float* conv4_w = (const float*)d_in[17];
    const float* conv4_b = (const float*)d_in[18];
    const float* conv5_w = (const float*)d_in[19];
    const float* conv5_b = (const float*)d_in[20];
    const float* kb_w    = (const float*)d_in[21];
    const float* kb_b    = (const float*)d_in[22];
    const float* ga1     = (const float*)d_in[23];
    const float* attg    = (const float*)d_in[24];
    const float* beta    = (const float*)d_in[25];
    const float* gamma   = (const float*)d_in[26];

    char* ws = (char*)d_ws;
    size_t off = 0;
    auto alloc = [&](size_t bytes) {
        void* r = ws + off;
        off += (bytes + 255) & ~(size_t)255;
        return r;
    };
    f16*     wpk   = (f16*)alloc(131072 * 2);
    f16*     wk2   = (f16*)alloc(20480 * 2);
    float*   cbuf  = (float*)alloc(256 * 4);
    float*   meanb = (float*)alloc(128 * 4);
    unsigned* bar  = (unsigned*)alloc(16);
    f16*     x1    = (f16*)alloc((size_t)P * 64 * 2);
    f16*     attb  = (f16*)alloc((size_t)P * 32 * 2);
    f16*     u1    = (f16*)alloc((size_t)P * 64 * 2);
    f16*     ufb   = (f16*)alloc((size_t)P * 64 * 2);
    f16*     xmid  = u1;   // u1 dead after stage B

    hipMemsetAsync(meanb, 0, 128 * 4, stream);
    hipMemsetAsync(bar, 0, 16, stream);

    KParams prm;
    prm.inp = inp;     prm.ln1w = ln1_w;  prm.ln1b = ln1_b;
    prm.c11aw = c11a_w; prm.c11ab = c11a_b;
    prm.x1 = x1;       prm.u1 = u1;       prm.meanb = meanb;
    prm.kbw = kb_w;    prm.kbb = kb_b;    prm.conv3w = conv3_w;
    prm.beta = beta;   prm.w4 = conv4_w;  prm.ln2w = ln2_w;
    prm.ln2b = ln2_b;  prm.b4 = conv4_b;  prm.w5 = conv5_w;
    prm.b5 = conv5_b;  prm.gamma = gamma; prm.conv3b = conv3_b;
    prm.wp = wpk;      prm.wk = wk2;      prm.cbuf = cbuf;
    prm.c2aw = c2a_w;  prm.c2ab = c2a_b;  prm.c2bw = c2b_w;
    prm.c2bb = c2b_b;  prm.attg = attg;   prm.att = attb;
    prm.c11bw = c11b_w; prm.c11bb = c11b_b; prm.uf = ufb;
    prm.ga1 = ga1;     prm.scaw = sca_w;  prm.scab = sca_b;
    prm.xmid = xmid;   prm.out = (float*)d_out;
    prm.bar = bar;

    kmega<<<512, 256, 0, stream>>>(prm);
}